// Round 3
// baseline (821.483 us; speedup 1.0000x reference)
//
#include <hip/hip_runtime.h>
#include <math.h>

#define Nn 98304
#define Ee 1572864
#define Cc 64
#define Hh 32
#define TT 128              // nodes per dst-tile
#define NT (Nn / TT)        // 768 tiles
#define HB 96               // histogram blocks
#define EPB (Ee / HB)       // 16384 edges per hist/bucket block
#define MSC (NT * HB)       // 73728 scan entries

// ws layout (4B units): dinv[Nn] | g[Nn*64] | agg[Nn*64] | C[Nn] | ebuf[Ee] | histG[MSC] | flag

__global__ void k_detect(const unsigned int* __restrict__ ei, int* __restrict__ flag) {
    // int64 little-endian indices (< 2^31) -> every odd 32-bit word is 0.
    if (threadIdx.x == 0 && blockIdx.x == 0) {
        int all0 = 1;
        for (int i = 0; i < 64; ++i)
            if (ei[2 * i + 1] != 0u) { all0 = 0; break; }
        *flag = all0;   // 1 => int64 layout
    }
}

__device__ __forceinline__ int load_idx(const void* ei, long e, int is64) {
    if (is64) return (int)((const long long*)ei)[e];
    return ((const int*)ei)[e];
}

__global__ __launch_bounds__(256) void k_zero(int* __restrict__ C) {
    int i = blockIdx.x * 256 + threadIdx.x;
    if (i < Nn) C[i] = 0;
}

__global__ __launch_bounds__(256) void k_count(const void* __restrict__ ei,
                                               const int* __restrict__ flag,
                                               int* __restrict__ C) {
    int e = blockIdx.x * 256 + threadIdx.x;
    int is64 = *flag;
    int d = load_idx(ei, (long)Ee + e, is64);
    atomicAdd(&C[d], 1);
}

__global__ __launch_bounds__(256) void k_dinv(const int* __restrict__ C,
                                              float* __restrict__ dinv) {
    int i = blockIdx.x * 256 + threadIdx.x;
    if (i < Nn) dinv[i] = rsqrtf((float)(C[i] + 1));   // +1 self-loop
}

// per-block tile histogram; histG[tile*HB + blk]
__global__ __launch_bounds__(1024) void k_hist(const void* __restrict__ ei,
                                               const int* __restrict__ flag,
                                               unsigned int* __restrict__ histG) {
    __shared__ unsigned int hl[NT];
    int t = threadIdx.x, b = blockIdx.x;
    if (t < NT) hl[t] = 0;
    __syncthreads();
    int is64 = *flag;
    long e0 = (long)b * EPB;
    for (int i = t; i < EPB; i += 1024) {
        int d = load_idx(ei, (long)Ee + e0 + i, is64);
        atomicAdd(&hl[d / TT], 1u);
    }
    __syncthreads();
    if (t < NT) histG[(long)t * HB + b] = hl[t];
}

// in-place exclusive scan of histG[MSC]
__global__ __launch_bounds__(1024) void k_scanT(unsigned int* __restrict__ histG) {
    __shared__ unsigned int part[1024];
    const int CH = MSC / 1024;   // 72
    int t = threadIdx.x;
    long base = (long)t * CH;
    unsigned int sum = 0;
    for (int i = 0; i < CH; ++i) sum += histG[base + i];
    part[t] = sum;
    __syncthreads();
    for (int off = 1; off < 1024; off <<= 1) {
        unsigned int v = (t >= off) ? part[t - off] : 0;
        __syncthreads();
        part[t] += v;
        __syncthreads();
    }
    unsigned int running = (t == 0) ? 0 : part[t - 1];
    for (int i = 0; i < CH; ++i) {
        unsigned int v = histG[base + i];
        histG[base + i] = running;
        running += v;
    }
}

// bucket edges into per-tile regions; ebuf = src(17b) | localdst(7b)<<17
__global__ __launch_bounds__(1024) void k_bucket(const void* __restrict__ ei,
                                                 const int* __restrict__ flag,
                                                 const unsigned int* __restrict__ histG,
                                                 unsigned int* __restrict__ ebuf) {
    __shared__ unsigned int cur[NT];
    int t = threadIdx.x, b = blockIdx.x;
    if (t < NT) cur[t] = histG[(long)t * HB + b];
    __syncthreads();
    int is64 = *flag;
    long e0 = (long)b * EPB;
    for (int i = t; i < EPB; i += 1024) {
        int s = load_idx(ei, e0 + i, is64);
        int d = load_idx(ei, (long)Ee + e0 + i, is64);
        unsigned int pos = atomicAdd(&cur[d / TT], 1u);
        ebuf[pos] = (unsigned int)s | ((unsigned int)(d & (TT - 1)) << 17);
    }
}

// g = (state @ conv_W) * dinv[row]
__global__ __launch_bounds__(256) void k_gemm(const float* __restrict__ state,
                                              const float* __restrict__ W,
                                              const float* __restrict__ dinv,
                                              float* __restrict__ g) {
    __shared__ float Wl[64 * 64];
    int t = threadIdx.x;
    #pragma unroll
    for (int i = 0; i < 16; ++i) Wl[i * 256 + t] = W[i * 256 + t];
    __syncthreads();
    int wave = t >> 6, lane = t & 63;
    int n0 = (blockIdx.x * 4 + wave) * 4;
    float acc0 = 0.f, acc1 = 0.f, acc2 = 0.f, acc3 = 0.f;
    const float* s0 = state + (long)n0 * 64;
    #pragma unroll 16
    for (int k = 0; k < 64; ++k) {
        float w = Wl[k * 64 + lane];
        acc0 = fmaf(s0[k],       w, acc0);
        acc1 = fmaf(s0[64 + k],  w, acc1);
        acc2 = fmaf(s0[128 + k], w, acc2);
        acc3 = fmaf(s0[192 + k], w, acc3);
    }
    float accs[4] = {acc0, acc1, acc2, acc3};
    #pragma unroll
    for (int r = 0; r < 4; ++r) {
        int n = n0 + r;
        g[(long)n * 64 + lane] = accs[r] * dinv[n];
    }
}

// per tile: LDS accumulate self + neighbor messages, write agg = acc*dinv
__global__ __launch_bounds__(256) void k_tile(const unsigned int* __restrict__ histG,
                                              const unsigned int* __restrict__ ebuf,
                                              const float* __restrict__ g,
                                              const float* __restrict__ dinv,
                                              float* __restrict__ agg) {
    __shared__ float acc[TT * 64];   // 32 KB; addr%32 == lane%32 -> free 2-way
    int t = threadIdx.x, tile = blockIdx.x;
    int wave = t >> 6, lane = t & 63;
    long nbase = (long)tile * TT;
    // init with self-loop term (g already scaled by dinv[src])
    #pragma unroll
    for (int i = t; i < TT * 64; i += 256) acc[i] = g[nbase * 64 + i];
    __syncthreads();
    int start = (int)histG[(long)tile * HB];
    int end = (tile < NT - 1) ? (int)histG[(long)(tile + 1) * HB] : Ee;
    for (int base = start + wave * 64; base < end; base += 256) {
        int m = min(64, end - base);
        unsigned int ev = (lane < m) ? ebuf[base + lane] : 0u;
        int j = 0;
        for (; j + 4 <= m; j += 4) {
            unsigned int u0 = __shfl(ev, j,     64);
            unsigned int u1 = __shfl(ev, j + 1, 64);
            unsigned int u2 = __shfl(ev, j + 2, 64);
            unsigned int u3 = __shfl(ev, j + 3, 64);
            float v0 = g[(long)(u0 & 0x1FFFF) * 64 + lane];
            float v1 = g[(long)(u1 & 0x1FFFF) * 64 + lane];
            float v2 = g[(long)(u2 & 0x1FFFF) * 64 + lane];
            float v3 = g[(long)(u3 & 0x1FFFF) * 64 + lane];
            atomicAdd(&acc[(u0 >> 17) * 64 + lane], v0);
            atomicAdd(&acc[(u1 >> 17) * 64 + lane], v1);
            atomicAdd(&acc[(u2 >> 17) * 64 + lane], v2);
            atomicAdd(&acc[(u3 >> 17) * 64 + lane], v3);
        }
        for (; j < m; ++j) {
            unsigned int u = __shfl(ev, j, 64);
            float v = g[(long)(u & 0x1FFFF) * 64 + lane];
            atomicAdd(&acc[(u >> 17) * 64 + lane], v);
        }
    }
    __syncthreads();
    #pragma unroll
    for (int i = t; i < TT * 64; i += 256)
        agg[nbase * 64 + i] = acc[i] * dinv[nbase + (i >> 6)];
}

// relu(agg + conv_b) + state -> MLP 64->32->32->1 -> softplus + 1e-20
__global__ __launch_bounds__(256) void k_final(const float* __restrict__ agg,
                                               const float* __restrict__ state,
                                               const float* __restrict__ conv_b,
                                               const float* __restrict__ W1,
                                               const float* __restrict__ b1,
                                               const float* __restrict__ W2,
                                               const float* __restrict__ b2,
                                               const float* __restrict__ W3,
                                               const float* __restrict__ b3,
                                               float* __restrict__ out) {
    __shared__ float sW1[Cc * Hh];
    __shared__ float sW2[Hh * Hh];
    __shared__ float sW3[Hh], sb1[Hh], sb2[Hh], scb[Cc];
    __shared__ float sb3;
    int t = threadIdx.x;
    for (int i = t; i < Cc * Hh; i += 256) sW1[i] = W1[i];
    for (int i = t; i < Hh * Hh; i += 256) sW2[i] = W2[i];
    if (t < Hh) { sW3[t] = W3[t]; sb1[t] = b1[t]; sb2[t] = b2[t]; }
    if (t < Cc) scb[t] = conv_b[t];
    if (t == 0) sb3 = b3[0];
    __syncthreads();

    int n = blockIdx.x * 256 + t;
    float x[Cc];
    #pragma unroll
    for (int k = 0; k < Cc; ++k) {
        float v = agg[(long)n * 64 + k] + scb[k];
        v = fmaxf(v, 0.f);
        x[k] = v + state[(long)n * 64 + k];
    }
    float h1[Hh];
    #pragma unroll
    for (int j = 0; j < Hh; ++j) h1[j] = sb1[j];
    #pragma unroll
    for (int k = 0; k < Cc; ++k) {
        float xv = x[k];
        #pragma unroll
        for (int j = 0; j < Hh; ++j) h1[j] = fmaf(xv, sW1[k * Hh + j], h1[j]);
    }
    #pragma unroll
    for (int j = 0; j < Hh; ++j) h1[j] = fmaxf(h1[j], 0.f);

    float h2[Hh];
    #pragma unroll
    for (int j = 0; j < Hh; ++j) h2[j] = sb2[j];
    #pragma unroll
    for (int k = 0; k < Hh; ++k) {
        float xv = h1[k];
        #pragma unroll
        for (int j = 0; j < Hh; ++j) h2[j] = fmaf(xv, sW2[k * Hh + j], h2[j]);
    }
    float y = sb3;
    #pragma unroll
    for (int j = 0; j < Hh; ++j) y = fmaf(fmaxf(h2[j], 0.f), sW3[j], y);

    float sp = fmaxf(y, 0.f) + log1pf(expf(-fabsf(y)));
    out[n] = sp + 1e-20f;
}

extern "C" void kernel_launch(void* const* d_in, const int* in_sizes, int n_in,
                              void* d_out, int out_size, void* d_ws, size_t ws_size,
                              hipStream_t stream) {
    const float* state  = (const float*)d_in[0];
    const void*  ei     = d_in[1];
    const float* conv_W = (const float*)d_in[2];
    const float* conv_b = (const float*)d_in[3];
    const float* W1 = (const float*)d_in[4];
    const float* b1 = (const float*)d_in[5];
    const float* W2 = (const float*)d_in[6];
    const float* b2 = (const float*)d_in[7];
    const float* W3 = (const float*)d_in[8];
    const float* b3 = (const float*)d_in[9];
    float* out = (float*)d_out;

    float*        dinv  = (float*)d_ws;
    float*        g     = dinv + Nn;
    float*        agg   = g + (size_t)Nn * 64;
    int*          C     = (int*)(agg + (size_t)Nn * 64);
    unsigned int* ebuf  = (unsigned int*)(C + Nn);
    unsigned int* histG = ebuf + Ee;
    int*          flag  = (int*)(histG + MSC);

    k_detect<<<1, 64, 0, stream>>>((const unsigned int*)ei, flag);
    k_zero<<<Nn / 256, 256, 0, stream>>>(C);
    k_count<<<Ee / 256, 256, 0, stream>>>(ei, flag, C);
    k_dinv<<<Nn / 256, 256, 0, stream>>>(C, dinv);
    k_hist<<<HB, 1024, 0, stream>>>(ei, flag, histG);
    k_scanT<<<1, 1024, 0, stream>>>(histG);
    k_bucket<<<HB, 1024, 0, stream>>>(ei, flag, histG, ebuf);
    k_gemm<<<Nn / 16, 256, 0, stream>>>(state, conv_W, dinv, g);
    k_tile<<<NT, 256, 0, stream>>>(histG, ebuf, g, dinv, agg);
    k_final<<<Nn / 256, 256, 0, stream>>>(agg, state, conv_b,
                                          W1, b1, W2, b2, W3, b3, out);
}

// Round 4
// 288.953 us; speedup vs baseline: 2.8430x; 2.8430x over previous
//
#include <hip/hip_runtime.h>
#include <math.h>

#define Nn 98304
#define Ee 1572864
#define Cc 64
#define Hh 32
#define TT 128              // nodes per dst-tile
#define NT (Nn / TT)        // 768 tiles
#define HB 96               // histogram blocks
#define EPB (Ee / HB)       // 16384 edges per hist/bucket block
#define MSC (NT * HB)       // 73728 scan entries

// ws layout (4B units):
//   dinv[Nn] | g[Nn*64] | rowOff[Nn] | histG[MSC] | flag | pad | srcs[Ee] | agg[Nn*64]
//   ebuf[Ee] ALIASES agg (ebuf dead before k_gather writes agg)

__global__ void k_detect(const unsigned int* __restrict__ ei, int* __restrict__ flag) {
    // int64 little-endian indices (< 2^31) -> every odd 32-bit word is 0.
    if (threadIdx.x == 0 && blockIdx.x == 0) {
        int all0 = 1;
        for (int i = 0; i < 64; ++i)
            if (ei[2 * i + 1] != 0u) { all0 = 0; break; }
        *flag = all0;   // 1 => int64 layout
    }
}

__device__ __forceinline__ int load_idx(const void* ei, long e, int is64) {
    if (is64) return (int)((const long long*)ei)[e];
    return ((const int*)ei)[e];
}

// per-block tile histogram; histG[tile*HB + blk]  (LDS atomics only)
__global__ __launch_bounds__(1024) void k_hist(const void* __restrict__ ei,
                                               const int* __restrict__ flag,
                                               unsigned int* __restrict__ histG) {
    __shared__ unsigned int hl[NT];
    int t = threadIdx.x, b = blockIdx.x;
    if (t < NT) hl[t] = 0;
    __syncthreads();
    int is64 = *flag;
    long e0 = (long)b * EPB;
    for (int i = t; i < EPB; i += 1024) {
        int d = load_idx(ei, (long)Ee + e0 + i, is64);
        atomicAdd(&hl[d / TT], 1u);
    }
    __syncthreads();
    if (t < NT) histG[(long)t * HB + b] = hl[t];
}

// in-place exclusive scan of histG[MSC]
__global__ __launch_bounds__(1024) void k_scanT(unsigned int* __restrict__ histG) {
    __shared__ unsigned int part[1024];
    const int CH = MSC / 1024;   // 72
    int t = threadIdx.x;
    long base = (long)t * CH;
    unsigned int sum = 0;
    for (int i = 0; i < CH; ++i) sum += histG[base + i];
    part[t] = sum;
    __syncthreads();
    for (int off = 1; off < 1024; off <<= 1) {
        unsigned int v = (t >= off) ? part[t - off] : 0;
        __syncthreads();
        part[t] += v;
        __syncthreads();
    }
    unsigned int running = (t == 0) ? 0 : part[t - 1];
    for (int i = 0; i < CH; ++i) {
        unsigned int v = histG[base + i];
        histG[base + i] = running;
        running += v;
    }
}

// bucket edges into per-tile contiguous regions; ebuf = src(17b) | localdst(7b)<<17
__global__ __launch_bounds__(1024) void k_bucket(const void* __restrict__ ei,
                                                 const int* __restrict__ flag,
                                                 const unsigned int* __restrict__ histG,
                                                 unsigned int* __restrict__ ebuf) {
    __shared__ unsigned int cur[NT];
    int t = threadIdx.x, b = blockIdx.x;
    if (t < NT) cur[t] = histG[(long)t * HB + b];
    __syncthreads();
    int is64 = *flag;
    long e0 = (long)b * EPB;
    for (int i = t; i < EPB; i += 1024) {
        int s = load_idx(ei, e0 + i, is64);
        int d = load_idx(ei, (long)Ee + e0 + i, is64);
        unsigned int pos = atomicAdd(&cur[d / TT], 1u);
        ebuf[pos] = (unsigned int)s | ((unsigned int)(d & (TT - 1)) << 17);
    }
}

// per tile: count local dsts (-> dinv, rowOff) then scatter src into srcs[]
// All global writes land inside this tile's own contiguous segment.
__global__ __launch_bounds__(256) void k_nodecnt(const unsigned int* __restrict__ histG,
                                                 const unsigned int* __restrict__ ebuf,
                                                 unsigned int* __restrict__ rowOff,
                                                 float* __restrict__ dinv,
                                                 unsigned int* __restrict__ srcs) {
    __shared__ unsigned int cnt[TT];
    __shared__ unsigned int sc[TT];
    __shared__ unsigned int cur[TT];
    int t = threadIdx.x, tile = blockIdx.x;
    int seg0 = (int)histG[(long)tile * HB];
    int seg1 = (tile < NT - 1) ? (int)histG[(long)(tile + 1) * HB] : Ee;
    if (t < TT) cnt[t] = 0;
    __syncthreads();
    for (int i = seg0 + t; i < seg1; i += 256)
        atomicAdd(&cnt[ebuf[i] >> 17], 1u);
    __syncthreads();
    if (t < TT) sc[t] = cnt[t];
    __syncthreads();
    #pragma unroll
    for (int off = 1; off < TT; off <<= 1) {
        unsigned int v = (t >= off && t < TT) ? sc[t - off] : 0;
        __syncthreads();
        if (t < TT) sc[t] += v;
        __syncthreads();
    }
    if (t < TT) {
        unsigned int excl = sc[t] - cnt[t];
        unsigned int start = (unsigned int)seg0 + excl;
        rowOff[(long)tile * TT + t] = start;
        cur[t] = start;
        dinv[(long)tile * TT + t] = rsqrtf((float)(cnt[t] + 1));   // +1 self-loop
    }
    __syncthreads();
    for (int i = seg0 + t; i < seg1; i += 256) {
        unsigned int u = ebuf[i];
        unsigned int pos = atomicAdd(&cur[u >> 17], 1u);
        srcs[pos] = u & 0x1FFFFu;
    }
}

// g = (state @ conv_W) * dinv[row]
__global__ __launch_bounds__(256) void k_gemm(const float* __restrict__ state,
                                              const float* __restrict__ W,
                                              const float* __restrict__ dinv,
                                              float* __restrict__ g) {
    __shared__ float Wl[64 * 64];
    int t = threadIdx.x;
    #pragma unroll
    for (int i = 0; i < 16; ++i) Wl[i * 256 + t] = W[i * 256 + t];
    __syncthreads();
    int wave = t >> 6, lane = t & 63;
    int n0 = (blockIdx.x * 4 + wave) * 4;
    float acc0 = 0.f, acc1 = 0.f, acc2 = 0.f, acc3 = 0.f;
    const float* s0 = state + (long)n0 * 64;
    #pragma unroll 16
    for (int k = 0; k < 64; ++k) {
        float w = Wl[k * 64 + lane];
        acc0 = fmaf(s0[k],       w, acc0);
        acc1 = fmaf(s0[64 + k],  w, acc1);
        acc2 = fmaf(s0[128 + k], w, acc2);
        acc3 = fmaf(s0[192 + k], w, acc3);
    }
    float accs[4] = {acc0, acc1, acc2, acc3};
    #pragma unroll
    for (int r = 0; r < 4; ++r) {
        int n = n0 + r;
        g[(long)n * 64 + lane] = accs[r] * dinv[n];
    }
}

// agg[n] = dinv[n] * (g[n] + sum_{src in row(n)} g[src])   (one wave per node)
__global__ __launch_bounds__(256) void k_gather(const unsigned int* __restrict__ rowOff,
                                                const unsigned int* __restrict__ srcs,
                                                const float* __restrict__ g,
                                                const float* __restrict__ dinv,
                                                float* __restrict__ agg) {
    int wave = threadIdx.x >> 6, lane = threadIdx.x & 63;
    int n = blockIdx.x * 4 + wave;
    int start = (int)rowOff[n];
    int end = (n < Nn - 1) ? (int)rowOff[n + 1] : Ee;
    float acc = g[(long)n * 64 + lane];   // self-loop term
    for (int base = start; base < end; base += 64) {
        int m = min(64, end - base);
        int sv = (lane < m) ? (int)srcs[base + lane] : 0;
        int j = 0;
        for (; j + 8 <= m; j += 8) {
            int s0 = __shfl(sv, j,     64);
            int s1 = __shfl(sv, j + 1, 64);
            int s2 = __shfl(sv, j + 2, 64);
            int s3 = __shfl(sv, j + 3, 64);
            int s4 = __shfl(sv, j + 4, 64);
            int s5 = __shfl(sv, j + 5, 64);
            int s6 = __shfl(sv, j + 6, 64);
            int s7 = __shfl(sv, j + 7, 64);
            float v0 = g[(long)s0 * 64 + lane];
            float v1 = g[(long)s1 * 64 + lane];
            float v2 = g[(long)s2 * 64 + lane];
            float v3 = g[(long)s3 * 64 + lane];
            float v4 = g[(long)s4 * 64 + lane];
            float v5 = g[(long)s5 * 64 + lane];
            float v6 = g[(long)s6 * 64 + lane];
            float v7 = g[(long)s7 * 64 + lane];
            acc += ((v0 + v1) + (v2 + v3)) + ((v4 + v5) + (v6 + v7));
        }
        for (; j + 4 <= m; j += 4) {
            int s0 = __shfl(sv, j,     64);
            int s1 = __shfl(sv, j + 1, 64);
            int s2 = __shfl(sv, j + 2, 64);
            int s3 = __shfl(sv, j + 3, 64);
            float v0 = g[(long)s0 * 64 + lane];
            float v1 = g[(long)s1 * 64 + lane];
            float v2 = g[(long)s2 * 64 + lane];
            float v3 = g[(long)s3 * 64 + lane];
            acc += (v0 + v1) + (v2 + v3);
        }
        for (; j < m; ++j) {
            int s = __shfl(sv, j, 64);
            acc += g[(long)s * 64 + lane];
        }
    }
    agg[(long)n * 64 + lane] = acc * dinv[n];
}

// relu(agg + conv_b) + state -> MLP 64->32->32->1 -> softplus + 1e-20
__global__ __launch_bounds__(256) void k_final(const float* __restrict__ agg,
                                               const float* __restrict__ state,
                                               const float* __restrict__ conv_b,
                                               const float* __restrict__ W1,
                                               const float* __restrict__ b1,
                                               const float* __restrict__ W2,
                                               const float* __restrict__ b2,
                                               const float* __restrict__ W3,
                                               const float* __restrict__ b3,
                                               float* __restrict__ out) {
    __shared__ float sW1[Cc * Hh];
    __shared__ float sW2[Hh * Hh];
    __shared__ float sW3[Hh], sb1[Hh], sb2[Hh], scb[Cc];
    __shared__ float sb3;
    int t = threadIdx.x;
    for (int i = t; i < Cc * Hh; i += 256) sW1[i] = W1[i];
    for (int i = t; i < Hh * Hh; i += 256) sW2[i] = W2[i];
    if (t < Hh) { sW3[t] = W3[t]; sb1[t] = b1[t]; sb2[t] = b2[t]; }
    if (t < Cc) scb[t] = conv_b[t];
    if (t == 0) sb3 = b3[0];
    __syncthreads();

    int n = blockIdx.x * 256 + t;
    float x[Cc];
    #pragma unroll
    for (int k = 0; k < Cc; ++k) {
        float v = agg[(long)n * 64 + k] + scb[k];
        v = fmaxf(v, 0.f);
        x[k] = v + state[(long)n * 64 + k];
    }
    float h1[Hh];
    #pragma unroll
    for (int j = 0; j < Hh; ++j) h1[j] = sb1[j];
    #pragma unroll
    for (int k = 0; k < Cc; ++k) {
        float xv = x[k];
        #pragma unroll
        for (int j = 0; j < Hh; ++j) h1[j] = fmaf(xv, sW1[k * Hh + j], h1[j]);
    }
    #pragma unroll
    for (int j = 0; j < Hh; ++j) h1[j] = fmaxf(h1[j], 0.f);

    float h2[Hh];
    #pragma unroll
    for (int j = 0; j < Hh; ++j) h2[j] = sb2[j];
    #pragma unroll
    for (int k = 0; k < Hh; ++k) {
        float xv = h1[k];
        #pragma unroll
        for (int j = 0; j < Hh; ++j) h2[j] = fmaf(xv, sW2[k * Hh + j], h2[j]);
    }
    float y = sb3;
    #pragma unroll
    for (int j = 0; j < Hh; ++j) y = fmaf(fmaxf(h2[j], 0.f), sW3[j], y);

    float sp = fmaxf(y, 0.f) + log1pf(expf(-fabsf(y)));
    out[n] = sp + 1e-20f;
}

extern "C" void kernel_launch(void* const* d_in, const int* in_sizes, int n_in,
                              void* d_out, int out_size, void* d_ws, size_t ws_size,
                              hipStream_t stream) {
    const float* state  = (const float*)d_in[0];
    const void*  ei     = d_in[1];
    const float* conv_W = (const float*)d_in[2];
    const float* conv_b = (const float*)d_in[3];
    const float* W1 = (const float*)d_in[4];
    const float* b1 = (const float*)d_in[5];
    const float* W2 = (const float*)d_in[6];
    const float* b2 = (const float*)d_in[7];
    const float* W3 = (const float*)d_in[8];
    const float* b3 = (const float*)d_in[9];
    float* out = (float*)d_out;

    float*        dinv   = (float*)d_ws;
    float*        g      = dinv + Nn;
    unsigned int* rowOff = (unsigned int*)(g + (size_t)Nn * 64);
    unsigned int* histG  = rowOff + Nn;
    int*          flag   = (int*)(histG + MSC);
    unsigned int* srcs   = (unsigned int*)(flag + 4);
    float*        agg    = (float*)(srcs + Ee);
    unsigned int* ebuf   = (unsigned int*)agg;   // alias: dead before k_gather writes agg

    k_detect<<<1, 64, 0, stream>>>((const unsigned int*)ei, flag);
    k_hist<<<HB, 1024, 0, stream>>>(ei, flag, histG);
    k_scanT<<<1, 1024, 0, stream>>>(histG);
    k_bucket<<<HB, 1024, 0, stream>>>(ei, flag, histG, ebuf);
    k_nodecnt<<<NT, 256, 0, stream>>>(histG, ebuf, rowOff, dinv, srcs);
    k_gemm<<<Nn / 16, 256, 0, stream>>>(state, conv_W, dinv, g);
    k_gather<<<Nn / 4, 256, 0, stream>>>(rowOff, srcs, g, dinv, agg);
    k_final<<<Nn / 256, 256, 0, stream>>>(agg, state, conv_b,
                                          W1, b1, W2, b2, W3, b3, out);
}

// Round 5
// 249.961 us; speedup vs baseline: 3.2864x; 1.1560x over previous
//
#include <hip/hip_runtime.h>
#include <math.h>

#define Nn 98304
#define Ee 1572864
#define Cc 64
#define Hh 32
#define TT 128              // nodes per dst-tile
#define NT (Nn / TT)        // 768 tiles
#define HB 96               // histogram blocks
#define EPB (Ee / HB)       // 16384 edges per hist/bucket block
#define MSC (NT * HB)       // 73728 scan entries

// ws layout (4B units):
//   dinv[Nn] | g[Nn*64] | rowOff[Nn] | histG[MSC] | srcs[Ee] | agg[Nn*64]
//   ebuf[Ee] ALIASES agg (ebuf dead before k_gather writes agg)

// int64 little-endian indices (< 2^31) -> odd 32-bit words are 0. All threads
// check the SAME 16 words -> deterministic agreement; for int32 these words
// are random indices, P(all 16 == 0) ~ (1e-5)^16.
__device__ __forceinline__ int detect64(const void* ei) {
    const unsigned int* u = (const unsigned int*)ei;
    int is64 = 1;
    #pragma unroll
    for (int i = 0; i < 16; ++i) is64 &= (u[2 * i + 1] == 0u);
    return is64;
}

__device__ __forceinline__ int load_idx(const void* ei, long e, int is64) {
    if (is64) return (int)((const long long*)ei)[e];
    return ((const int*)ei)[e];
}

// per-block tile histogram; histG[tile*HB + blk]  (LDS atomics only)
__global__ __launch_bounds__(1024) void k_hist(const void* __restrict__ ei,
                                               unsigned int* __restrict__ histG) {
    __shared__ unsigned int hl[NT];
    int t = threadIdx.x, b = blockIdx.x;
    if (t < NT) hl[t] = 0;
    __syncthreads();
    int is64 = detect64(ei);
    long e0 = (long)b * EPB;
    for (int i = t; i < EPB; i += 1024) {
        int d = load_idx(ei, (long)Ee + e0 + i, is64);
        atomicAdd(&hl[d / TT], 1u);
    }
    __syncthreads();
    if (t < NT) histG[(long)t * HB + b] = hl[t];
}

// in-place exclusive scan of histG[MSC]
__global__ __launch_bounds__(1024) void k_scanT(unsigned int* __restrict__ histG) {
    __shared__ unsigned int part[1024];
    const int CH = MSC / 1024;   // 72
    int t = threadIdx.x;
    long base = (long)t * CH;
    unsigned int sum = 0;
    for (int i = 0; i < CH; ++i) sum += histG[base + i];
    part[t] = sum;
    __syncthreads();
    for (int off = 1; off < 1024; off <<= 1) {
        unsigned int v = (t >= off) ? part[t - off] : 0;
        __syncthreads();
        part[t] += v;
        __syncthreads();
    }
    unsigned int running = (t == 0) ? 0 : part[t - 1];
    for (int i = 0; i < CH; ++i) {
        unsigned int v = histG[base + i];
        histG[base + i] = running;
        running += v;
    }
}

// bucket edges into per-tile contiguous regions; ebuf = src(17b) | localdst(7b)<<17
__global__ __launch_bounds__(1024) void k_bucket(const void* __restrict__ ei,
                                                 const unsigned int* __restrict__ histG,
                                                 unsigned int* __restrict__ ebuf) {
    __shared__ unsigned int cur[NT];
    int t = threadIdx.x, b = blockIdx.x;
    if (t < NT) cur[t] = histG[(long)t * HB + b];
    __syncthreads();
    int is64 = detect64(ei);
    long e0 = (long)b * EPB;
    for (int i = t; i < EPB; i += 1024) {
        int s = load_idx(ei, e0 + i, is64);
        int d = load_idx(ei, (long)Ee + e0 + i, is64);
        unsigned int pos = atomicAdd(&cur[d / TT], 1u);
        ebuf[pos] = (unsigned int)s | ((unsigned int)(d & (TT - 1)) << 17);
    }
}

// per tile: count local dsts (-> dinv, rowOff) then scatter src into srcs[]
// All global writes land inside this tile's own contiguous segment.
__global__ __launch_bounds__(256) void k_nodecnt(const unsigned int* __restrict__ histG,
                                                 const unsigned int* __restrict__ ebuf,
                                                 unsigned int* __restrict__ rowOff,
                                                 float* __restrict__ dinv,
                                                 unsigned int* __restrict__ srcs) {
    __shared__ unsigned int cnt[TT];
    __shared__ unsigned int sc[TT];
    __shared__ unsigned int cur[TT];
    int t = threadIdx.x, tile = blockIdx.x;
    int seg0 = (int)histG[(long)tile * HB];
    int seg1 = (tile < NT - 1) ? (int)histG[(long)(tile + 1) * HB] : Ee;
    if (t < TT) cnt[t] = 0;
    __syncthreads();
    for (int i = seg0 + t; i < seg1; i += 256)
        atomicAdd(&cnt[ebuf[i] >> 17], 1u);
    __syncthreads();
    if (t < TT) sc[t] = cnt[t];
    __syncthreads();
    #pragma unroll
    for (int off = 1; off < TT; off <<= 1) {
        unsigned int v = (t >= off && t < TT) ? sc[t - off] : 0;
        __syncthreads();
        if (t < TT) sc[t] += v;
        __syncthreads();
    }
    if (t < TT) {
        unsigned int excl = sc[t] - cnt[t];
        unsigned int start = (unsigned int)seg0 + excl;
        rowOff[(long)tile * TT + t] = start;
        cur[t] = start;
        dinv[(long)tile * TT + t] = rsqrtf((float)(cnt[t] + 1));   // +1 self-loop
    }
    __syncthreads();
    for (int i = seg0 + t; i < seg1; i += 256) {
        unsigned int u = ebuf[i];
        unsigned int pos = atomicAdd(&cur[u >> 17], 1u);
        srcs[pos] = u & 0x1FFFFu;
    }
}

// g = (state @ conv_W) * dinv[row]
// LDS-tiled register-blocked: 64 rows/block, thread = 4x4 output tile.
__global__ __launch_bounds__(256) void k_gemm(const float* __restrict__ state,
                                              const float* __restrict__ W,
                                              const float* __restrict__ dinv,
                                              float* __restrict__ g) {
    __shared__ float Wl[64 * 64];       // row-major [k][c]
    __shared__ float Al[64 * 68];       // row-major [r][k], stride 68: 16B-aligned, bank-spread
    int t = threadIdx.x;
    long n0 = (long)blockIdx.x * 64;

    const float4* W4 = (const float4*)W;
    float4* Wl4 = (float4*)Wl;
    #pragma unroll
    for (int i = 0; i < 4; ++i) Wl4[i * 256 + t] = W4[i * 256 + t];

    const float4* S4 = (const float4*)(state) + n0 * 16;
    #pragma unroll
    for (int i = 0; i < 4; ++i) {
        int f4 = t + i * 256;           // float4 index into 64x64 tile
        int r = f4 >> 4, k0 = (f4 & 15) * 4;
        *(float4*)(Al + r * 68 + k0) = S4[f4];
    }
    __syncthreads();

    int r0 = (t >> 4) * 4;              // 4 rows
    int c0 = (t & 15) * 4;              // 4 cols
    float acc[4][4] = {{0.f}};
    #pragma unroll
    for (int kk = 0; kk < 64; kk += 4) {
        float4 a4[4], w4[4];
        #pragma unroll
        for (int i = 0; i < 4; ++i) a4[i] = *(const float4*)(Al + (r0 + i) * 68 + kk);
        #pragma unroll
        for (int j = 0; j < 4; ++j) w4[j] = *(const float4*)(Wl + (kk + j) * 64 + c0);
        const float* aa = (const float*)a4;   // aa[i*4+j]
        const float* ww = (const float*)w4;   // ww[j*4+c]
        #pragma unroll
        for (int i = 0; i < 4; ++i)
            #pragma unroll
            for (int j = 0; j < 4; ++j) {
                float av = aa[i * 4 + j];
                #pragma unroll
                for (int c = 0; c < 4; ++c)
                    acc[i][c] = fmaf(av, ww[j * 4 + c], acc[i][c]);
            }
    }
    #pragma unroll
    for (int i = 0; i < 4; ++i) {
        long n = n0 + r0 + i;
        float dv = dinv[n];
        float4 o;
        o.x = acc[i][0] * dv; o.y = acc[i][1] * dv;
        o.z = acc[i][2] * dv; o.w = acc[i][3] * dv;
        *(float4*)(g + n * 64 + c0) = o;
    }
}

// agg[n] = dinv[n] * (g[n] + sum_{src in row(n)} g[src])   (one wave per node)
__global__ __launch_bounds__(256) void k_gather(const unsigned int* __restrict__ rowOff,
                                                const unsigned int* __restrict__ srcs,
                                                const float* __restrict__ g,
                                                const float* __restrict__ dinv,
                                                float* __restrict__ agg) {
    int wave = threadIdx.x >> 6, lane = threadIdx.x & 63;
    int n = blockIdx.x * 4 + wave;
    int start = (int)rowOff[n];
    int end = (n < Nn - 1) ? (int)rowOff[n + 1] : Ee;
    float acc = g[(long)n * 64 + lane];   // self-loop term
    for (int base = start; base < end; base += 64) {
        int m = min(64, end - base);
        int sv = (lane < m) ? (int)srcs[base + lane] : 0;
        int j = 0;
        for (; j + 8 <= m; j += 8) {
            int s0 = __shfl(sv, j,     64);
            int s1 = __shfl(sv, j + 1, 64);
            int s2 = __shfl(sv, j + 2, 64);
            int s3 = __shfl(sv, j + 3, 64);
            int s4 = __shfl(sv, j + 4, 64);
            int s5 = __shfl(sv, j + 5, 64);
            int s6 = __shfl(sv, j + 6, 64);
            int s7 = __shfl(sv, j + 7, 64);
            float v0 = g[(long)s0 * 64 + lane];
            float v1 = g[(long)s1 * 64 + lane];
            float v2 = g[(long)s2 * 64 + lane];
            float v3 = g[(long)s3 * 64 + lane];
            float v4 = g[(long)s4 * 64 + lane];
            float v5 = g[(long)s5 * 64 + lane];
            float v6 = g[(long)s6 * 64 + lane];
            float v7 = g[(long)s7 * 64 + lane];
            acc += ((v0 + v1) + (v2 + v3)) + ((v4 + v5) + (v6 + v7));
        }
        for (; j + 4 <= m; j += 4) {
            int s0 = __shfl(sv, j,     64);
            int s1 = __shfl(sv, j + 1, 64);
            int s2 = __shfl(sv, j + 2, 64);
            int s3 = __shfl(sv, j + 3, 64);
            float v0 = g[(long)s0 * 64 + lane];
            float v1 = g[(long)s1 * 64 + lane];
            float v2 = g[(long)s2 * 64 + lane];
            float v3 = g[(long)s3 * 64 + lane];
            acc += (v0 + v1) + (v2 + v3);
        }
        for (; j < m; ++j) {
            int s = __shfl(sv, j, 64);
            acc += g[(long)s * 64 + lane];
        }
    }
    agg[(long)n * 64 + lane] = acc * dinv[n];
}

// relu(agg + conv_b) + state -> MLP 64->32->32->1 -> softplus + 1e-20
__global__ __launch_bounds__(256) void k_final(const float* __restrict__ agg,
                                               const float* __restrict__ state,
                                               const float* __restrict__ conv_b,
                                               const float* __restrict__ W1,
                                               const float* __restrict__ b1,
                                               const float* __restrict__ W2,
                                               const float* __restrict__ b2,
                                               const float* __restrict__ W3,
                                               const float* __restrict__ b3,
                                               float* __restrict__ out) {
    __shared__ float sW1[Cc * Hh];
    __shared__ float sW2[Hh * Hh];
    __shared__ float sW3[Hh], sb1[Hh], sb2[Hh], scb[Cc];
    __shared__ float sb3;
    int t = threadIdx.x;
    for (int i = t; i < Cc * Hh; i += 256) sW1[i] = W1[i];
    for (int i = t; i < Hh * Hh; i += 256) sW2[i] = W2[i];
    if (t < Hh) { sW3[t] = W3[t]; sb1[t] = b1[t]; sb2[t] = b2[t]; }
    if (t < Cc) scb[t] = conv_b[t];
    if (t == 0) sb3 = b3[0];
    __syncthreads();

    int n = blockIdx.x * 256 + t;
    float x[Cc];
    #pragma unroll
    for (int k = 0; k < Cc; ++k) {
        float v = agg[(long)n * 64 + k] + scb[k];
        v = fmaxf(v, 0.f);
        x[k] = v + state[(long)n * 64 + k];
    }
    float h1[Hh];
    #pragma unroll
    for (int j = 0; j < Hh; ++j) h1[j] = sb1[j];
    #pragma unroll
    for (int k = 0; k < Cc; ++k) {
        float xv = x[k];
        #pragma unroll
        for (int j = 0; j < Hh; ++j) h1[j] = fmaf(xv, sW1[k * Hh + j], h1[j]);
    }
    #pragma unroll
    for (int j = 0; j < Hh; ++j) h1[j] = fmaxf(h1[j], 0.f);

    float h2[Hh];
    #pragma unroll
    for (int j = 0; j < Hh; ++j) h2[j] = sb2[j];
    #pragma unroll
    for (int k = 0; k < Hh; ++k) {
        float xv = h1[k];
        #pragma unroll
        for (int j = 0; j < Hh; ++j) h2[j] = fmaf(xv, sW2[k * Hh + j], h2[j]);
    }
    float y = sb3;
    #pragma unroll
    for (int j = 0; j < Hh; ++j) y = fmaf(fmaxf(h2[j], 0.f), sW3[j], y);

    float sp = fmaxf(y, 0.f) + log1pf(expf(-fabsf(y)));
    out[n] = sp + 1e-20f;
}

extern "C" void kernel_launch(void* const* d_in, const int* in_sizes, int n_in,
                              void* d_out, int out_size, void* d_ws, size_t ws_size,
                              hipStream_t stream) {
    const float* state  = (const float*)d_in[0];
    const void*  ei     = d_in[1];
    const float* conv_W = (const float*)d_in[2];
    const float* conv_b = (const float*)d_in[3];
    const float* W1 = (const float*)d_in[4];
    const float* b1 = (const float*)d_in[5];
    const float* W2 = (const float*)d_in[6];
    const float* b2 = (const float*)d_in[7];
    const float* W3 = (const float*)d_in[8];
    const float* b3 = (const float*)d_in[9];
    float* out = (float*)d_out;

    float*        dinv   = (float*)d_ws;
    float*        g      = dinv + Nn;
    unsigned int* rowOff = (unsigned int*)(g + (size_t)Nn * 64);
    unsigned int* histG  = rowOff + Nn;
    unsigned int* srcs   = histG + MSC;
    float*        agg    = (float*)(srcs + Ee);
    unsigned int* ebuf   = (unsigned int*)agg;   // alias: dead before k_gather writes agg

    k_hist<<<HB, 1024, 0, stream>>>(ei, histG);
    k_scanT<<<1, 1024, 0, stream>>>(histG);
    k_bucket<<<HB, 1024, 0, stream>>>(ei, histG, ebuf);
    k_nodecnt<<<NT, 256, 0, stream>>>(histG, ebuf, rowOff, dinv, srcs);
    k_gemm<<<Nn / 64, 256, 0, stream>>>(state, conv_W, dinv, g);
    k_gather<<<Nn / 4, 256, 0, stream>>>(rowOff, srcs, g, dinv, agg);
    k_final<<<Nn / 256, 256, 0, stream>>>(agg, state, conv_b,
                                          W1, b1, W2, b2, W3, b3, out);
}

// Round 6
// 209.368 us; speedup vs baseline: 3.9236x; 1.1939x over previous
//
#include <hip/hip_runtime.h>
#include <math.h>

#define Nn 98304
#define Ee 1572864
#define Cc 64
#define Hh 32
#define TT 128              // nodes per dst-tile
#define NT (Nn / TT)        // 768 tiles
#define HB 96               // bucket blocks
#define EPB (Ee / HB)       // 16384 edges per bucket block
#define CAP 2560            // ebuf slots per tile (mean 2048, sigma~45 -> 11 sigma slack)

// ws layout (4B units):
//   dinv[Nn] | gb[Nn*32] (bf16 x64/row) | rowOff[Nn] | rowEnd[Nn] | tileCursor[NT]
//   | srcs[NT*CAP] | agg[Nn*64]
//   ebuf[NT*CAP] ALIASES agg (ebuf dead before k_gather writes agg)

// int64 little-endian indices (< 2^31) -> odd 32-bit words are 0. All threads
// check the SAME 16 words -> deterministic agreement.
__device__ __forceinline__ int detect64(const void* ei) {
    const unsigned int* u = (const unsigned int*)ei;
    int is64 = 1;
    #pragma unroll
    for (int i = 0; i < 16; ++i) is64 &= (u[2 * i + 1] == 0u);
    return is64;
}

__device__ __forceinline__ int load_idx(const void* ei, long e, int is64) {
    if (is64) return (int)((const long long*)ei)[e];
    return ((const int*)ei)[e];
}

__device__ __forceinline__ unsigned short f2bf(float x) {
    union { float f; unsigned int u; } v; v.f = x;
    unsigned int r = v.u + 0x7FFFu + ((v.u >> 16) & 1u);   // RNE
    return (unsigned short)(r >> 16);
}
__device__ __forceinline__ float bf2f(unsigned short h) {
    union { unsigned int u; float f; } v; v.u = ((unsigned int)h) << 16;
    return v.f;
}

__global__ __launch_bounds__(1024) void k_init(unsigned int* __restrict__ tileCursor) {
    int t = threadIdx.x;
    if (t < NT) tileCursor[t] = (unsigned int)(t * CAP);
}

// LDS histogram -> atomic per-tile reservation -> scatter into reserved runs.
// All global writes: contiguous-ish runs inside this tile's own region.
__global__ __launch_bounds__(1024) void k_bucket(const void* __restrict__ ei,
                                                 unsigned int* __restrict__ tileCursor,
                                                 unsigned int* __restrict__ ebuf) {
    __shared__ unsigned int hl[NT];
    __shared__ unsigned int cur[NT];
    int t = threadIdx.x, b = blockIdx.x;
    if (t < NT) hl[t] = 0;
    __syncthreads();
    int is64 = detect64(ei);
    long e0 = (long)b * EPB;
    for (int i = t; i < EPB; i += 1024) {
        int d = load_idx(ei, (long)Ee + e0 + i, is64);
        atomicAdd(&hl[d / TT], 1u);
    }
    __syncthreads();
    if (t < NT) cur[t] = atomicAdd(&tileCursor[t], hl[t]);   // reserve
    __syncthreads();
    for (int i = t; i < EPB; i += 1024) {
        int s = load_idx(ei, e0 + i, is64);
        int d = load_idx(ei, (long)Ee + e0 + i, is64);
        unsigned int pos = atomicAdd(&cur[d / TT], 1u);
        ebuf[pos] = (unsigned int)s | ((unsigned int)(d & (TT - 1)) << 17);
    }
}

// per tile: count local dsts (-> dinv, rowOff, rowEnd) then scatter src into srcs[]
__global__ __launch_bounds__(256) void k_nodecnt(const unsigned int* __restrict__ tileCursor,
                                                 const unsigned int* __restrict__ ebuf,
                                                 unsigned int* __restrict__ rowOff,
                                                 unsigned int* __restrict__ rowEnd,
                                                 float* __restrict__ dinv,
                                                 unsigned int* __restrict__ srcs) {
    __shared__ unsigned int cnt[TT];
    __shared__ unsigned int sc[TT];
    __shared__ unsigned int cur[TT];
    int t = threadIdx.x, tile = blockIdx.x;
    int seg0 = tile * CAP;
    int seg1 = (int)tileCursor[tile];
    if (t < TT) cnt[t] = 0;
    __syncthreads();
    for (int i = seg0 + t; i < seg1; i += 256)
        atomicAdd(&cnt[ebuf[i] >> 17], 1u);
    __syncthreads();
    if (t < TT) sc[t] = cnt[t];
    __syncthreads();
    #pragma unroll
    for (int off = 1; off < TT; off <<= 1) {
        unsigned int v = (t >= off && t < TT) ? sc[t - off] : 0;
        __syncthreads();
        if (t < TT) sc[t] += v;
        __syncthreads();
    }
    if (t < TT) {
        unsigned int start = (unsigned int)seg0 + sc[t] - cnt[t];
        rowOff[(long)tile * TT + t] = start;
        rowEnd[(long)tile * TT + t] = start + cnt[t];
        cur[t] = start;
        dinv[(long)tile * TT + t] = rsqrtf((float)(cnt[t] + 1));   // +1 self-loop
    }
    __syncthreads();
    for (int i = seg0 + t; i < seg1; i += 256) {
        unsigned int u = ebuf[i];
        unsigned int pos = atomicAdd(&cur[u >> 17], 1u);
        srcs[pos] = u & 0x1FFFFu;
    }
}

// gb = bf16( (state @ conv_W) * dinv[row] )
// LDS-tiled register-blocked: 64 rows/block, thread = 4x4 output tile.
__global__ __launch_bounds__(256) void k_gemm(const float* __restrict__ state,
                                              const float* __restrict__ W,
                                              const float* __restrict__ dinv,
                                              unsigned short* __restrict__ gb) {
    __shared__ float Wl[64 * 64];       // row-major [k][c]
    __shared__ float Al[64 * 68];       // row-major [r][k], stride 68
    int t = threadIdx.x;
    long n0 = (long)blockIdx.x * 64;

    const float4* W4 = (const float4*)W;
    float4* Wl4 = (float4*)Wl;
    #pragma unroll
    for (int i = 0; i < 4; ++i) Wl4[i * 256 + t] = W4[i * 256 + t];

    const float4* S4 = (const float4*)(state) + n0 * 16;
    #pragma unroll
    for (int i = 0; i < 4; ++i) {
        int f4 = t + i * 256;
        int r = f4 >> 4, k0 = (f4 & 15) * 4;
        *(float4*)(Al + r * 68 + k0) = S4[f4];
    }
    __syncthreads();

    int r0 = (t >> 4) * 4;
    int c0 = (t & 15) * 4;
    float acc[4][4] = {{0.f}};
    #pragma unroll
    for (int kk = 0; kk < 64; kk += 4) {
        float4 a4[4], w4[4];
        #pragma unroll
        for (int i = 0; i < 4; ++i) a4[i] = *(const float4*)(Al + (r0 + i) * 68 + kk);
        #pragma unroll
        for (int j = 0; j < 4; ++j) w4[j] = *(const float4*)(Wl + (kk + j) * 64 + c0);
        const float* aa = (const float*)a4;
        const float* ww = (const float*)w4;
        #pragma unroll
        for (int i = 0; i < 4; ++i)
            #pragma unroll
            for (int j = 0; j < 4; ++j) {
                float av = aa[i * 4 + j];
                #pragma unroll
                for (int c = 0; c < 4; ++c)
                    acc[i][c] = fmaf(av, ww[j * 4 + c], acc[i][c]);
            }
    }
    #pragma unroll
    for (int i = 0; i < 4; ++i) {
        long n = n0 + r0 + i;
        float dv = dinv[n];
        ushort4 o;
        o.x = f2bf(acc[i][0] * dv); o.y = f2bf(acc[i][1] * dv);
        o.z = f2bf(acc[i][2] * dv); o.w = f2bf(acc[i][3] * dv);
        *(ushort4*)(gb + n * 64 + c0) = o;
    }
}

// agg[n] = dinv[n] * (g[n] + sum_{src in row(n)} g[src])   (one wave per node)
__global__ __launch_bounds__(256) void k_gather(const unsigned int* __restrict__ rowOff,
                                                const unsigned int* __restrict__ rowEnd,
                                                const unsigned int* __restrict__ srcs,
                                                const unsigned short* __restrict__ gb,
                                                const float* __restrict__ dinv,
                                                float* __restrict__ agg) {
    int wave = threadIdx.x >> 6, lane = threadIdx.x & 63;
    int n = blockIdx.x * 4 + wave;
    int start = (int)rowOff[n];
    int end = (int)rowEnd[n];
    float acc = bf2f(gb[(long)n * 64 + lane]);   // self-loop term
    for (int base = start; base < end; base += 64) {
        int m = min(64, end - base);
        int sv = (lane < m) ? (int)srcs[base + lane] : 0;
        int j = 0;
        for (; j + 8 <= m; j += 8) {
            int s0 = __shfl(sv, j,     64);
            int s1 = __shfl(sv, j + 1, 64);
            int s2 = __shfl(sv, j + 2, 64);
            int s3 = __shfl(sv, j + 3, 64);
            int s4 = __shfl(sv, j + 4, 64);
            int s5 = __shfl(sv, j + 5, 64);
            int s6 = __shfl(sv, j + 6, 64);
            int s7 = __shfl(sv, j + 7, 64);
            float v0 = bf2f(gb[(long)s0 * 64 + lane]);
            float v1 = bf2f(gb[(long)s1 * 64 + lane]);
            float v2 = bf2f(gb[(long)s2 * 64 + lane]);
            float v3 = bf2f(gb[(long)s3 * 64 + lane]);
            float v4 = bf2f(gb[(long)s4 * 64 + lane]);
            float v5 = bf2f(gb[(long)s5 * 64 + lane]);
            float v6 = bf2f(gb[(long)s6 * 64 + lane]);
            float v7 = bf2f(gb[(long)s7 * 64 + lane]);
            acc += ((v0 + v1) + (v2 + v3)) + ((v4 + v5) + (v6 + v7));
        }
        for (; j + 4 <= m; j += 4) {
            int s0 = __shfl(sv, j,     64);
            int s1 = __shfl(sv, j + 1, 64);
            int s2 = __shfl(sv, j + 2, 64);
            int s3 = __shfl(sv, j + 3, 64);
            float v0 = bf2f(gb[(long)s0 * 64 + lane]);
            float v1 = bf2f(gb[(long)s1 * 64 + lane]);
            float v2 = bf2f(gb[(long)s2 * 64 + lane]);
            float v3 = bf2f(gb[(long)s3 * 64 + lane]);
            acc += (v0 + v1) + (v2 + v3);
        }
        for (; j < m; ++j) {
            int s = __shfl(sv, j, 64);
            acc += bf2f(gb[(long)s * 64 + lane]);
        }
    }
    agg[(long)n * 64 + lane] = acc * dinv[n];
}

// relu(agg + conv_b) + state -> MLP 64->32->32->1 -> softplus + 1e-20
__global__ __launch_bounds__(256) void k_final(const float* __restrict__ agg,
                                               const float* __restrict__ state,
                                               const float* __restrict__ conv_b,
                                               const float* __restrict__ W1,
                                               const float* __restrict__ b1,
                                               const float* __restrict__ W2,
                                               const float* __restrict__ b2,
                                               const float* __restrict__ W3,
                                               const float* __restrict__ b3,
                                               float* __restrict__ out) {
    __shared__ float sW1[Cc * Hh];
    __shared__ float sW2[Hh * Hh];
    __shared__ float sW3[Hh], sb1[Hh], sb2[Hh], scb[Cc];
    __shared__ float sb3;
    int t = threadIdx.x;
    for (int i = t; i < Cc * Hh; i += 256) sW1[i] = W1[i];
    for (int i = t; i < Hh * Hh; i += 256) sW2[i] = W2[i];
    if (t < Hh) { sW3[t] = W3[t]; sb1[t] = b1[t]; sb2[t] = b2[t]; }
    if (t < Cc) scb[t] = conv_b[t];
    if (t == 0) sb3 = b3[0];
    __syncthreads();

    int n = blockIdx.x * 256 + t;
    const float4* a4p = (const float4*)(agg + (long)n * 64);
    const float4* s4p = (const float4*)(state + (long)n * 64);
    float x[Cc];
    #pragma unroll
    for (int k4 = 0; k4 < 16; ++k4) {
        float4 a = a4p[k4];
        float4 s = s4p[k4];
        x[k4 * 4 + 0] = fmaxf(a.x + scb[k4 * 4 + 0], 0.f) + s.x;
        x[k4 * 4 + 1] = fmaxf(a.y + scb[k4 * 4 + 1], 0.f) + s.y;
        x[k4 * 4 + 2] = fmaxf(a.z + scb[k4 * 4 + 2], 0.f) + s.z;
        x[k4 * 4 + 3] = fmaxf(a.w + scb[k4 * 4 + 3], 0.f) + s.w;
    }
    float h1[Hh];
    #pragma unroll
    for (int j = 0; j < Hh; ++j) h1[j] = sb1[j];
    #pragma unroll
    for (int k = 0; k < Cc; ++k) {
        float xv = x[k];
        #pragma unroll
        for (int j = 0; j < Hh; ++j) h1[j] = fmaf(xv, sW1[k * Hh + j], h1[j]);
    }
    #pragma unroll
    for (int j = 0; j < Hh; ++j) h1[j] = fmaxf(h1[j], 0.f);

    float h2[Hh];
    #pragma unroll
    for (int j = 0; j < Hh; ++j) h2[j] = sb2[j];
    #pragma unroll
    for (int k = 0; k < Hh; ++k) {
        float xv = h1[k];
        #pragma unroll
        for (int j = 0; j < Hh; ++j) h2[j] = fmaf(xv, sW2[k * Hh + j], h2[j]);
    }
    float y = sb3;
    #pragma unroll
    for (int j = 0; j < Hh; ++j) y = fmaf(fmaxf(h2[j], 0.f), sW3[j], y);

    float sp = fmaxf(y, 0.f) + log1pf(expf(-fabsf(y)));
    out[n] = sp + 1e-20f;
}

extern "C" void kernel_launch(void* const* d_in, const int* in_sizes, int n_in,
                              void* d_out, int out_size, void* d_ws, size_t ws_size,
                              hipStream_t stream) {
    const float* state  = (const float*)d_in[0];
    const void*  ei     = d_in[1];
    const float* conv_W = (const float*)d_in[2];
    const float* conv_b = (const float*)d_in[3];
    const float* W1 = (const float*)d_in[4];
    const float* b1 = (const float*)d_in[5];
    const float* W2 = (const float*)d_in[6];
    const float* b2 = (const float*)d_in[7];
    const float* W3 = (const float*)d_in[8];
    const float* b3 = (const float*)d_in[9];
    float* out = (float*)d_out;

    float*          dinv       = (float*)d_ws;
    unsigned short* gb         = (unsigned short*)(dinv + Nn);
    unsigned int*   rowOff     = (unsigned int*)(gb + (size_t)Nn * 64);
    unsigned int*   rowEnd     = rowOff + Nn;
    unsigned int*   tileCursor = rowEnd + Nn;
    unsigned int*   srcs       = tileCursor + NT;
    float*          agg        = (float*)(srcs + (size_t)NT * CAP);
    unsigned int*   ebuf       = (unsigned int*)agg;   // alias: dead before k_gather writes agg

    k_init<<<1, 1024, 0, stream>>>(tileCursor);
    k_bucket<<<HB, 1024, 0, stream>>>(ei, tileCursor, ebuf);
    k_nodecnt<<<NT, 256, 0, stream>>>(tileCursor, ebuf, rowOff, rowEnd, dinv, srcs);
    k_gemm<<<Nn / 64, 256, 0, stream>>>(state, conv_W, dinv, gb);
    k_gather<<<Nn / 4, 256, 0, stream>>>(rowOff, rowEnd, srcs, gb, dinv, agg);
    k_final<<<Nn / 256, 256, 0, stream>>>(agg, state, conv_b,
                                          W1, b1, W2, b2, W3, b3, out);
}

// Round 7
// 198.292 us; speedup vs baseline: 4.1428x; 1.0559x over previous
//
#include <hip/hip_runtime.h>
#include <math.h>

#define Nn 98304
#define Ee 1572864
#define Cc 64
#define Hh 32
#define TT 128              // nodes per dst-tile
#define NT (Nn / TT)        // 768 tiles
#define HB 256              // bucket blocks
#define EPB (Ee / HB)       // 6144 edges per bucket block
#define CAPT 2560           // staged edges per tile (mean 2048, sigma~45 -> +11 sigma)
#define GN 64               // nodes per fused gather+final block

// ws layout (4B units):
//   dinv[Nn] | gb[Nn*32] (bf16 x64/row) | rowOff[Nn] | rowEnd[Nn]
//   | aux[HB*NT] | ebuf[Ee] | srcs[NT*CAPT]

// int64 little-endian indices (< 2^31) -> odd 32-bit words are 0. All threads
// check the SAME 16 words -> deterministic agreement.
__device__ __forceinline__ int detect64(const void* ei) {
    const unsigned int* u = (const unsigned int*)ei;
    int is64 = 1;
    #pragma unroll
    for (int i = 0; i < 16; ++i) is64 &= (u[2 * i + 1] == 0u);
    return is64;
}

__device__ __forceinline__ int load_idx(const void* ei, long e, int is64) {
    if (is64) return (int)((const long long*)ei)[e];
    return ((const int*)ei)[e];
}

__device__ __forceinline__ unsigned short f2bf(float x) {
    union { float f; unsigned int u; } v; v.f = x;
    unsigned int r = v.u + 0x7FFFu + ((v.u >> 16) & 1u);   // RNE
    return (unsigned short)(r >> 16);
}
__device__ __forceinline__ float bf2f(unsigned short h) {
    union { unsigned int u; float f; } v; v.u = ((unsigned int)h) << 16;
    return v.f;
}

// Block-local counting sort of this block's EPB edges by dst-tile.
// No global atomics. ebuf region [b*EPB, (b+1)*EPB) fully packed, tile-ordered.
// aux[b*NT + t] = localOff(16b) | cnt<<16 for tile t within block b's region.
__global__ __launch_bounds__(1024) void k_bucket(const void* __restrict__ ei,
                                                 unsigned int* __restrict__ aux,
                                                 unsigned int* __restrict__ ebuf) {
    __shared__ unsigned int hl[NT];
    __shared__ unsigned int off[NT];
    int t = threadIdx.x, b = blockIdx.x;
    if (t < NT) hl[t] = 0;
    __syncthreads();
    int is64 = detect64(ei);
    long e0 = (long)b * EPB;
    #pragma unroll
    for (int i = 0; i < EPB / 1024; ++i) {     // 6 iters
        int d = load_idx(ei, (long)Ee + e0 + i * 1024 + t, is64);
        atomicAdd(&hl[d >> 7], 1u);            // d / TT
    }
    __syncthreads();
    if (t < NT) off[t] = hl[t];
    __syncthreads();
    // inclusive Hillis-Steele scan over 768
    for (int s = 1; s < NT; s <<= 1) {
        unsigned int v = (t < NT && t >= s) ? off[t - s] : 0u;
        __syncthreads();
        if (t < NT) off[t] += v;
        __syncthreads();
    }
    if (t < NT) {
        unsigned int ex = off[t] - hl[t];      // exclusive
        aux[(long)b * NT + t] = ex | (hl[t] << 16);
        off[t] = ex;                           // reuse as cursor
    }
    __syncthreads();
    #pragma unroll
    for (int i = 0; i < EPB / 1024; ++i) {
        long e = e0 + i * 1024 + t;
        int s = load_idx(ei, e, is64);
        int d = load_idx(ei, (long)Ee + e, is64);
        unsigned int pos = atomicAdd(&off[d >> 7], 1u);   // LDS atomic
        ebuf[(long)b * EPB + pos] = (unsigned int)s | ((unsigned int)(d & (TT - 1)) << 17);
    }
}

// per tile: pull this tile's runs from all HB blocks into LDS, count local
// dsts (-> dinv, rowOff, rowEnd), scatter src into tile-private srcs region.
__global__ __launch_bounds__(256) void k_nodecnt(const unsigned int* __restrict__ aux,
                                                 const unsigned int* __restrict__ ebuf,
                                                 unsigned int* __restrict__ rowOff,
                                                 unsigned int* __restrict__ rowEnd,
                                                 float* __restrict__ dinv,
                                                 unsigned int* __restrict__ srcs) {
    __shared__ unsigned int stage[CAPT];   // 10 KB
    __shared__ unsigned int rb[HB];
    __shared__ unsigned int cnt[TT];
    __shared__ unsigned int sc[TT];
    __shared__ unsigned int cur[TT];
    int t = threadIdx.x, tile = blockIdx.x;     // blockDim == HB == 256
    unsigned int av = aux[(long)t * NT + tile];
    unsigned int roff = av & 0xFFFFu, rcnt = av >> 16;
    rb[t] = rcnt;
    __syncthreads();
    for (int s = 1; s < HB; s <<= 1) {          // inclusive scan over 256
        unsigned int v = (t >= s) ? rb[t - s] : 0u;
        __syncthreads();
        rb[t] += v;
        __syncthreads();
    }
    unsigned int mybase = rb[t] - rcnt;
    for (unsigned int i = 0; i < rcnt; ++i)
        stage[mybase + i] = ebuf[(long)t * EPB + roff + i];
    if (t < TT) cnt[t] = 0;
    __syncthreads();
    int total = (int)rb[HB - 1];
    for (int i = t; i < total; i += 256)
        atomicAdd(&cnt[stage[i] >> 17], 1u);
    __syncthreads();
    if (t < TT) sc[t] = cnt[t];
    __syncthreads();
    #pragma unroll
    for (int off = 1; off < TT; off <<= 1) {
        unsigned int v = (t >= off && t < TT) ? sc[t - off] : 0u;
        __syncthreads();
        if (t < TT) sc[t] += v;
        __syncthreads();
    }
    if (t < TT) {
        unsigned int start = (unsigned int)(tile * CAPT) + sc[t] - cnt[t];
        rowOff[(long)tile * TT + t] = start;
        rowEnd[(long)tile * TT + t] = start + cnt[t];
        cur[t] = start;
        dinv[(long)tile * TT + t] = rsqrtf((float)(cnt[t] + 1));   // +1 self-loop
    }
    __syncthreads();
    for (int i = t; i < total; i += 256) {
        unsigned int u = stage[i];
        unsigned int pos = atomicAdd(&cur[u >> 17], 1u);
        srcs[pos] = u & 0x1FFFFu;
    }
}

// gb = bf16( (state @ conv_W) * dinv[row] )
__global__ __launch_bounds__(256) void k_gemm(const float* __restrict__ state,
                                              const float* __restrict__ W,
                                              const float* __restrict__ dinv,
                                              unsigned short* __restrict__ gb) {
    __shared__ float Wl[64 * 64];       // [k][c]
    __shared__ float Al[64 * 68];       // [r][k], stride 68
    int t = threadIdx.x;
    long n0 = (long)blockIdx.x * 64;

    const float4* W4 = (const float4*)W;
    float4* Wl4 = (float4*)Wl;
    #pragma unroll
    for (int i = 0; i < 4; ++i) Wl4[i * 256 + t] = W4[i * 256 + t];

    const float4* S4 = (const float4*)(state) + n0 * 16;
    #pragma unroll
    for (int i = 0; i < 4; ++i) {
        int f4 = t + i * 256;
        int r = f4 >> 4, k0 = (f4 & 15) * 4;
        *(float4*)(Al + r * 68 + k0) = S4[f4];
    }
    __syncthreads();

    int r0 = (t >> 4) * 4;
    int c0 = (t & 15) * 4;
    float acc[4][4] = {{0.f}};
    #pragma unroll
    for (int kk = 0; kk < 64; kk += 4) {
        float4 a4[4], w4[4];
        #pragma unroll
        for (int i = 0; i < 4; ++i) a4[i] = *(const float4*)(Al + (r0 + i) * 68 + kk);
        #pragma unroll
        for (int j = 0; j < 4; ++j) w4[j] = *(const float4*)(Wl + (kk + j) * 64 + c0);
        const float* aa = (const float*)a4;
        const float* ww = (const float*)w4;
        #pragma unroll
        for (int i = 0; i < 4; ++i)
            #pragma unroll
            for (int j = 0; j < 4; ++j) {
                float av = aa[i * 4 + j];
                #pragma unroll
                for (int c = 0; c < 4; ++c)
                    acc[i][c] = fmaf(av, ww[j * 4 + c], acc[i][c]);
            }
    }
    #pragma unroll
    for (int i = 0; i < 4; ++i) {
        long n = n0 + r0 + i;
        float dv = dinv[n];
        ushort4 o;
        o.x = f2bf(acc[i][0] * dv); o.y = f2bf(acc[i][1] * dv);
        o.z = f2bf(acc[i][2] * dv); o.w = f2bf(acc[i][3] * dv);
        *(ushort4*)(gb + n * 64 + c0) = o;
    }
}

// Fused gather + epilogue MLP. 512 threads (8 waves), GN=64 nodes/block.
// Gather: wave w handles nodes w*8..w*8+8, agg row -> LDS (stride 68).
// MLP: 8 threads/node off LDS; out written directly.
__global__ __launch_bounds__(512) void k_gf(const unsigned int* __restrict__ rowOff,
                                            const unsigned int* __restrict__ rowEnd,
                                            const unsigned int* __restrict__ srcs,
                                            const unsigned short* __restrict__ gb,
                                            const float* __restrict__ dinv,
                                            const float* __restrict__ state,
                                            const float* __restrict__ conv_b,
                                            const float* __restrict__ W1,
                                            const float* __restrict__ b1,
                                            const float* __restrict__ W2,
                                            const float* __restrict__ b2,
                                            const float* __restrict__ W3,
                                            const float* __restrict__ b3,
                                            float* __restrict__ out) {
    __shared__ float sa[GN * 68];       // agg rows then x then h2 (17.4 KB)
    __shared__ float hs[GN * 34];       // h1 rows (8.7 KB)
    __shared__ float sW1[Cc * Hh];
    __shared__ float sW2[Hh * Hh];
    __shared__ float sW3[Hh], sb1[Hh], sb2[Hh], scb[Cc];
    __shared__ float sb3;
    int t = threadIdx.x;
    int wave = t >> 6, lane = t & 63;
    long n0 = (long)blockIdx.x * GN;

    for (int i = t; i < Cc * Hh; i += 512) sW1[i] = W1[i];
    for (int i = t; i < Hh * Hh; i += 512) sW2[i] = W2[i];
    if (t < Hh) { sW3[t] = W3[t]; sb1[t] = b1[t]; sb2[t] = b2[t]; }
    if (t >= 64 && t < 128) scb[t - 64] = conv_b[t - 64];
    if (t == 511) sb3 = b3[0];

    // --- gather phase ---
    #pragma unroll
    for (int jj = 0; jj < 8; ++jj) {
        int j = wave * 8 + jj;
        long n = n0 + j;
        int start = (int)rowOff[n];
        int end = (int)rowEnd[n];
        float acc = bf2f(gb[n * 64 + lane]);   // self-loop
        for (int base = start; base < end; base += 64) {
            int m = min(64, end - base);
            int sv = (lane < m) ? (int)srcs[base + lane] : 0;
            int q = 0;
            for (; q + 8 <= m; q += 8) {
                int s0 = __shfl(sv, q,     64);
                int s1 = __shfl(sv, q + 1, 64);
                int s2 = __shfl(sv, q + 2, 64);
                int s3 = __shfl(sv, q + 3, 64);
                int s4 = __shfl(sv, q + 4, 64);
                int s5 = __shfl(sv, q + 5, 64);
                int s6 = __shfl(sv, q + 6, 64);
                int s7 = __shfl(sv, q + 7, 64);
                float v0 = bf2f(gb[(long)s0 * 64 + lane]);
                float v1 = bf2f(gb[(long)s1 * 64 + lane]);
                float v2 = bf2f(gb[(long)s2 * 64 + lane]);
                float v3 = bf2f(gb[(long)s3 * 64 + lane]);
                float v4 = bf2f(gb[(long)s4 * 64 + lane]);
                float v5 = bf2f(gb[(long)s5 * 64 + lane]);
                float v6 = bf2f(gb[(long)s6 * 64 + lane]);
                float v7 = bf2f(gb[(long)s7 * 64 + lane]);
                acc += ((v0 + v1) + (v2 + v3)) + ((v4 + v5) + (v6 + v7));
            }
            for (; q < m; ++q) {
                int s = __shfl(sv, q, 64);
                acc += bf2f(gb[(long)s * 64 + lane]);
            }
        }
        sa[j * 68 + lane] = acc * dinv[n];
    }
    __syncthreads();

    // --- 2a: x = relu(agg + cb) + state, in place (thread: node j, 8 chans) ---
    {
        int j = t >> 3, o = t & 7;
        long n = n0 + j;
        int k0 = o * 8;
        const float4* sp4 = (const float4*)(state + n * 64 + k0);
        float4 s0 = sp4[0], s1 = sp4[1];
        float* r = sa + j * 68 + k0;
        r[0] = fmaxf(r[0] + scb[k0 + 0], 0.f) + s0.x;
        r[1] = fmaxf(r[1] + scb[k0 + 1], 0.f) + s0.y;
        r[2] = fmaxf(r[2] + scb[k0 + 2], 0.f) + s0.z;
        r[3] = fmaxf(r[3] + scb[k0 + 3], 0.f) + s0.w;
        r[4] = fmaxf(r[4] + scb[k0 + 4], 0.f) + s1.x;
        r[5] = fmaxf(r[5] + scb[k0 + 5], 0.f) + s1.y;
        r[6] = fmaxf(r[6] + scb[k0 + 6], 0.f) + s1.z;
        r[7] = fmaxf(r[7] + scb[k0 + 7], 0.f) + s1.w;
    }
    __syncthreads();

    // --- 2b: h1 = relu(x@W1 + b1) (thread: node j, 4 outputs) ---
    {
        int j = t >> 3, o = t & 7;
        int c0 = o * 4;
        float a0 = sb1[c0], a1 = sb1[c0 + 1], a2 = sb1[c0 + 2], a3 = sb1[c0 + 3];
        #pragma unroll
        for (int k = 0; k < Cc; ++k) {
            float xv = sa[j * 68 + k];
            float4 w = *(const float4*)(sW1 + k * Hh + c0);
            a0 = fmaf(xv, w.x, a0); a1 = fmaf(xv, w.y, a1);
            a2 = fmaf(xv, w.z, a2); a3 = fmaf(xv, w.w, a3);
        }
        float* r = hs + j * 34 + c0;
        r[0] = fmaxf(a0, 0.f); r[1] = fmaxf(a1, 0.f);
        r[2] = fmaxf(a2, 0.f); r[3] = fmaxf(a3, 0.f);
    }
    __syncthreads();

    // --- 2c: h2 = relu(h1@W2 + b2) -> sa (thread: node j, 4 outputs) ---
    {
        int j = t >> 3, o = t & 7;
        int c0 = o * 4;
        float a0 = sb2[c0], a1 = sb2[c0 + 1], a2 = sb2[c0 + 2], a3 = sb2[c0 + 3];
        #pragma unroll
        for (int k = 0; k < Hh; ++k) {
            float xv = hs[j * 34 + k];
            float4 w = *(const float4*)(sW2 + k * Hh + c0);
            a0 = fmaf(xv, w.x, a0); a1 = fmaf(xv, w.y, a1);
            a2 = fmaf(xv, w.z, a2); a3 = fmaf(xv, w.w, a3);
        }
        float* r = sa + j * 68 + c0;
        r[0] = fmaxf(a0, 0.f); r[1] = fmaxf(a1, 0.f);
        r[2] = fmaxf(a2, 0.f); r[3] = fmaxf(a3, 0.f);
    }
    __syncthreads();

    // --- 2d: y = h2@W3 + b3; softplus (one thread per node) ---
    if (t < GN) {
        float y = sb3;
        #pragma unroll
        for (int k = 0; k < Hh; ++k) y = fmaf(sa[t * 68 + k], sW3[k], y);
        float sp = fmaxf(y, 0.f) + log1pf(expf(-fabsf(y)));
        out[n0 + t] = sp + 1e-20f;
    }
}

extern "C" void kernel_launch(void* const* d_in, const int* in_sizes, int n_in,
                              void* d_out, int out_size, void* d_ws, size_t ws_size,
                              hipStream_t stream) {
    const float* state  = (const float*)d_in[0];
    const void*  ei     = d_in[1];
    const float* conv_W = (const float*)d_in[2];
    const float* conv_b = (const float*)d_in[3];
    const float* W1 = (const float*)d_in[4];
    const float* b1 = (const float*)d_in[5];
    const float* W2 = (const float*)d_in[6];
    const float* b2 = (const float*)d_in[7];
    const float* W3 = (const float*)d_in[8];
    const float* b3 = (const float*)d_in[9];
    float* out = (float*)d_out;

    float*          dinv   = (float*)d_ws;
    unsigned short* gb     = (unsigned short*)(dinv + Nn);
    unsigned int*   rowOff = (unsigned int*)(gb + (size_t)Nn * 64);
    unsigned int*   rowEnd = rowOff + Nn;
    unsigned int*   aux    = rowEnd + Nn;
    unsigned int*   ebuf   = aux + (size_t)HB * NT;
    unsigned int*   srcs   = ebuf + Ee;

    k_bucket<<<HB, 1024, 0, stream>>>(ei, aux, ebuf);
    k_nodecnt<<<NT, 256, 0, stream>>>(aux, ebuf, rowOff, rowEnd, dinv, srcs);
    k_gemm<<<Nn / 64, 256, 0, stream>>>(state, conv_W, dinv, gb);
    k_gf<<<Nn / GN, 512, 0, stream>>>(rowOff, rowEnd, srcs, gb, dinv, state, conv_b,
                                      W1, b1, W2, b2, W3, b3, out);
}